// Round 10
// baseline (202.375 us; speedup 1.0000x reference)
//
#include <hip/hip_runtime.h>

typedef _Float16 f16x8 __attribute__((ext_vector_type(8)));
typedef _Float16 f16x4 __attribute__((ext_vector_type(4)));
typedef _Float16 f16x2 __attribute__((ext_vector_type(2)));
typedef __fp16 hf16x2 __attribute__((ext_vector_type(2)));
typedef float f32x4 __attribute__((ext_vector_type(4)));

__device__ __forceinline__ float fast_exp2(float x) {
#if __has_builtin(__builtin_amdgcn_exp2f)
  return __builtin_amdgcn_exp2f(x);
#else
  return exp2f(x);
#endif
}

__device__ __forceinline__ f16x2 pk_cvt(float a, float b) {
#if __has_builtin(__builtin_amdgcn_cvt_pkrtz)
  union { hf16x2 h; f16x2 f; } u;
  u.h = __builtin_amdgcn_cvt_pkrtz(a, b);
  return u.f;
#else
  f16x2 r; r[0] = (_Float16)a; r[1] = (_Float16)b; return r;
#endif
}

// v_permlane32_swap_b32: x <- {x.lanes[0:31], y.lanes[0:31]},
//                        y <- {x.lanes[32:63], y.lanes[32:63]}
__device__ __forceinline__ void qswap32(int& x, int& y) {
  asm("v_permlane32_swap_b32 %0, %1" : "+v"(x), "+v"(y));
}

// key-index involution: swap bits 2 and 3 (sigma == pi, self-inverse)
__device__ __forceinline__ int swz23(int c) {
  return (c & ~12) | ((c & 4) << 1) | ((c & 8) >> 1);
}

// ---------------- fused f32 -> f16 convert prepass ----------------
__global__ void cvt_all(const float* __restrict__ x,
                        const float* __restrict__ Wq, const float* __restrict__ Wk,
                        const float* __restrict__ Wv, const float* __restrict__ Wo,
                        _Float16* __restrict__ xf, _Float16* __restrict__ wf) {
  int g = blockIdx.x * blockDim.x + threadIdx.x;
  const float* src;
  _Float16* dst;
  if (g < 524288) {
    src = x + (size_t)g * 8;
    dst = xf + (size_t)g * 8;
  } else {
    int g2 = g - 524288;
    int z = g2 >> 15, off = g2 & 32767;
    const float* W = (z == 0) ? Wq : (z == 1) ? Wk : (z == 2) ? Wv : Wo;
    src = W + (size_t)off * 8;
    dst = wf + (size_t)z * 262144 + (size_t)off * 8;
  }
  f32x4 a = *(const f32x4*)src;
  f32x4 b = *(const f32x4*)(src + 4);
  f16x8 o;
  o[0] = (_Float16)a[0]; o[1] = (_Float16)a[1];
  o[2] = (_Float16)a[2]; o[3] = (_Float16)a[3];
  o[4] = (_Float16)b[0]; o[5] = (_Float16)b[1];
  o[6] = (_Float16)b[2]; o[7] = (_Float16)b[3];
  *(f16x8*)dst = o;
}

// ---------------- fused QKV projection: y = x @ W^T + b ----------------
// v3: BK=32 double-buffer -> LDS 40960 B -> 3 blocks/CU = the 768-block grid
// exactly (tail-free), keeping the 1-barrier/step prefetch schedule and XCD
// swizzle (X panel per XCD stays L2-hot, reused 12x).
// Q,K (z!=2): swapped-operand MFMA -> f16x4 stores of 4 consecutive d.
// V (z==2): normal order, written TRANSPOSED [bh][d][t].
__global__ __launch_bounds__(256, 3)
void qkv_gemm(const _Float16* __restrict__ X, const _Float16* __restrict__ Wf,
              const float* __restrict__ bq, const float* __restrict__ bk,
              const float* __restrict__ bv, _Float16* __restrict__ dst3) {
  __shared__ __align__(16) _Float16 As[2][128][40];
  __shared__ __align__(16) _Float16 Bs[2][128][40];
  // XCD swizzle (bijective, 768 = 8 xcd x 96)
  const int id = (blockIdx.z * 4 + blockIdx.y) * 64 + blockIdx.x;
  const int xcd = id & 7, s = id >> 3;          // s in [0,96)
  const int m0 = (xcd * 8 + (s & 7)) * 128;     // m-tile in [0,64)
  const int yz = s >> 3;                        // [0,12)
  const int n0 = (yz & 3) * 128;
  const int z = yz >> 2;
  const _Float16* Wz = Wf + (size_t)z * 262144;
  const float* bias = (z == 0) ? bq : (z == 1 ? bk : bv);
  _Float16* dst = dst3 + (size_t)z * 4194304;
  const float scale = (z == 0) ? 0.18033688011112042f : 1.0f;

  const int t = threadIdx.x;
  const int lane = t & 63, wave = t >> 6;
  const int quad = lane >> 4, col = lane & 15;
  const int wm = (wave & 1) * 64, wn = (wave >> 1) * 64;
  // BK=32 staging: 128x32 f16 per tile, 1 f16x8/thread per matrix per i
  const int sr2 = t >> 2, sc2 = (t & 3) * 8;    // rows sr2 + 64*i, cols sc2

  f32x4 acc[4][4] = {};
  f16x8 areg[2], breg[2];

#define GLOAD(K0)                                                             \
  {                                                                           \
    _Pragma("unroll") for (int i = 0; i < 2; i++) {                           \
      areg[i] = *(const f16x8*)&X[(size_t)(m0 + sr2 + 64 * i) * 512 + (K0) + sc2]; \
      breg[i] = *(const f16x8*)&Wz[(size_t)(n0 + sr2 + 64 * i) * 512 + (K0) + sc2]; \
    }                                                                         \
  }

#define GSTAGE(B)                                                             \
  {                                                                           \
    _Pragma("unroll") for (int i = 0; i < 2; i++) {                           \
      *(f16x8*)&As[(B)][sr2 + 64 * i][sc2] = areg[i];                         \
      *(f16x8*)&Bs[(B)][sr2 + 64 * i][sc2] = breg[i];                         \
    }                                                                         \
  }

#define GCOMP(B, SWAP)                                                        \
  {                                                                           \
    f16x8 a[4], b[4];                                                         \
    _Pragma("unroll") for (int i = 0; i < 4; i++) {                           \
      a[i] = *(const f16x8*)&As[(B)][wm + i * 16 + col][quad * 8];            \
      b[i] = *(const f16x8*)&Bs[(B)][wn + i * 16 + col][quad * 8];            \
    }                                                                         \
    _Pragma("unroll") for (int mi = 0; mi < 4; mi++)                          \
      _Pragma("unroll") for (int ni = 0; ni < 4; ni++)                        \
        acc[mi][ni] = (SWAP)                                                  \
            ? __builtin_amdgcn_mfma_f32_16x16x32_f16(b[ni], a[mi],            \
                                                     acc[mi][ni], 0, 0, 0)    \
            : __builtin_amdgcn_mfma_f32_16x16x32_f16(a[mi], b[ni],            \
                                                     acc[mi][ni], 0, 0, 0);   \
  }

  if (z != 2) {
    GLOAD(0); GSTAGE(0); GLOAD(32);
    __syncthreads();
#pragma unroll
    for (int k = 0; k < 15; k++) {
      GCOMP(k & 1, true);
      GSTAGE((k + 1) & 1);
      if (k < 14) GLOAD((k + 2) * 32);
      __syncthreads();
    }
    GCOMP(1, true);
    // Q,K: [bh][t][d], f16x4 of 4 consecutive d per token
#pragma unroll
    for (int ni = 0; ni < 4; ni++) {
      int nb = n0 + wn + ni * 16 + quad * 4;   // 4 consecutive features
      int h = nb >> 6, d0 = nb & 63;
      f32x4 bb = *(const f32x4*)&bias[nb];
#pragma unroll
      for (int mi = 0; mi < 4; mi++) {
        int m = m0 + wm + mi * 16 + col;
        int b = m >> 12, tt = m & 4095;
        f16x4 ov;
#pragma unroll
        for (int r = 0; r < 4; r++)
          ov[r] = (_Float16)((acc[mi][ni][r] + bb[r]) * scale);
        *(f16x4*)&dst[((size_t)(b * 8 + h) * 4096 + tt) * 64 + d0] = ov;
      }
    }
  } else {
    GLOAD(0); GSTAGE(0); GLOAD(32);
    __syncthreads();
#pragma unroll
    for (int k = 0; k < 15; k++) {
      GCOMP(k & 1, false);
      GSTAGE((k + 1) & 1);
      if (k < 14) GLOAD((k + 2) * 32);
      __syncthreads();
    }
    GCOMP(1, false);
    // V: [bh][d][t] layout, vectorized f16x4 along t
#pragma unroll
    for (int ni = 0; ni < 4; ni++) {
      int n = n0 + wn + ni * 16 + col;
      float bv_ = bias[n];
      int h = n >> 6, d = n & 63;
#pragma unroll
      for (int mi = 0; mi < 4; mi++) {
        int m = m0 + wm + mi * 16 + quad * 4;
        int b = m >> 12, tt = m & 4095;
        f16x4 ov;
#pragma unroll
        for (int r = 0; r < 4; r++) ov[r] = (_Float16)(acc[mi][ni][r] + bv_);
        *(f16x4*)&dst[((size_t)((b * 8 + h) * 64 + d)) * 4096 + tt] = ov;
      }
    }
  }
#undef GLOAD
#undef GSTAGE
#undef GCOMP
}

// ---------------- flash attention (R6-verified, ~92-94 us) -----------------
// 128-key KV tiles, 32 q/wave, reg-prefetch dbuf, XCD swizzle (2 bh/XCD),
// PV at K=32 via permlane32_swap + bit2<->3 V swizzle, lsum on VALU,
// setprio around MFMA clusters.
__global__ __launch_bounds__(256, 2)
void attn_kernel(const _Float16* __restrict__ Q, const _Float16* __restrict__ K,
                 const _Float16* __restrict__ V, _Float16* __restrict__ O) {
  __shared__ __align__(16) _Float16 Ks[2][128][72];
  __shared__ __align__(16) _Float16 Vt[2][64][136]; // pitch 136: 16B-aligned rows

  const int t = threadIdx.x;
  const int lane = t & 63, wave = t >> 6;
  const int quad = lane >> 4, col = lane & 15;
  // XCD swizzle: id%8 = XCD (round-robin dispatch); give each XCD 2 whole bh
  const int id = blockIdx.y * 32 + blockIdx.x;
  const int xcd = id & 7, slot = id >> 3;
  const int bh = xcd * 2 + (slot >> 5);
  const int q0 = (slot & 31) * 128;
  const _Float16* Qb = Q + (size_t)bh * 4096 * 64;
  const _Float16* Kbh = K + (size_t)bh * 4096 * 64;
  const _Float16* Vg = V + (size_t)bh * 64 * 4096;   // [d][t]

  // staging coords
  const int sr = (t * 8) >> 6, sc = (t * 8) & 63;    // K rows: r = sr + 32*i
  const int vrow = t >> 4, vcol = (t & 15) * 8;      // V^T rows: d = vrow + 16*it
  const int vc0 = swz23(vcol);                       // sigma(vcol)
  const int vc1 = swz23(vcol + 4);                   // sigma(vcol+4)

  // Q as B-fragment: B[n=query=mt*16+col][k=d=ks*32+quad*8+j]
  f16x8 qf[2][2];
#pragma unroll
  for (int mt = 0; mt < 2; mt++)
#pragma unroll
    for (int ks = 0; ks < 2; ks++)
      qf[mt][ks] = *(const f16x8*)&Qb[(size_t)(q0 + wave * 32 + mt * 16 + col) * 64 +
                                      ks * 32 + quad * 8];

  const f32x4 fz = {0.f, 0.f, 0.f, 0.f};

  f16x8 kreg[4], vreg[4];
  // prologue: load tile 0
#pragma unroll
  for (int i = 0; i < 4; i++)
    kreg[i] = *(const f16x8*)&Kbh[(size_t)(sr + 32 * i) * 64 + sc];
#pragma unroll
  for (int it = 0; it < 4; it++)
    vreg[it] = *(const f16x8*)&Vg[(size_t)(it * 16 + vrow) * 4096 + vcol];
#pragma unroll
  for (int i = 0; i < 4; i++)
    *(f16x8*)&Ks[0][sr + 32 * i][sc] = kreg[i];
#pragma unroll
  for (int it = 0; it < 4; it++) {
    f16x4 lo, hi;
#pragma unroll
    for (int u = 0; u < 4; u++) { lo[u] = vreg[it][u]; hi[u] = vreg[it][u + 4]; }
    *(f16x4*)&Vt[0][it * 16 + vrow][vc0] = lo;
    *(f16x4*)&Vt[0][it * 16 + vrow][vc1] = hi;
  }
  __syncthreads();

  // o_acc[mt][dt][r] = O^T[d=dt*16+quad*4+r][query=mt*16+col]
  f32x4 o_acc[2][4] = {};
  // per-lane partial row-sum of P for query=col, keys {nt*16+quad*4+r, all nt,j}
  float lsum[2] = {0.f, 0.f};

  for (int j = 0; j < 32; j++) {
    const int buf = j & 1;
    // prefetch tile j+1 into registers (latency hidden behind compute)
    if (j + 1 < 32) {
      const _Float16* Kb = Kbh + (size_t)(j + 1) * 128 * 64;
#pragma unroll
      for (int i = 0; i < 4; i++)
        kreg[i] = *(const f16x8*)&Kb[(size_t)(sr + 32 * i) * 64 + sc];
#pragma unroll
      for (int it = 0; it < 4; it++)
        vreg[it] = *(const f16x8*)&Vg[(size_t)(it * 16 + vrow) * 4096 +
                                      (j + 1) * 128 + vcol];
    }

    // S^T[key][query]: s[mt][nt][r] = S[q=mt*16+col][key=nt*16+quad*4+r]
    f32x4 s[2][8];
    __builtin_amdgcn_s_setprio(1);
#pragma unroll
    for (int nt = 0; nt < 8; nt++) {
      f16x8 kf = *(const f16x8*)&Ks[buf][nt * 16 + col][quad * 8];
#pragma unroll
      for (int mt = 0; mt < 2; mt++)
        s[mt][nt] = __builtin_amdgcn_mfma_f32_16x16x32_f16(kf, qf[mt][0], fz, 0, 0, 0);
    }
#pragma unroll
    for (int nt = 0; nt < 8; nt++) {
      f16x8 kf = *(const f16x8*)&Ks[buf][nt * 16 + col][32 + quad * 8];
#pragma unroll
      for (int mt = 0; mt < 2; mt++)
        s[mt][nt] = __builtin_amdgcn_mfma_f32_16x16x32_f16(kf, qf[mt][1], s[mt][nt], 0, 0, 0);
    }
    __builtin_amdgcn_s_setprio(0);

    // P = exp2(S^T): bare v_exp_f32 + packed f32->f16; l-accum on VALU pipe
    f16x4 pf[2][8];
#pragma unroll
    for (int mt = 0; mt < 2; mt++) {
#pragma unroll
      for (int nt = 0; nt < 8; nt++) {
        float p0 = fast_exp2(s[mt][nt][0]);
        float p1 = fast_exp2(s[mt][nt][1]);
        float p2 = fast_exp2(s[mt][nt][2]);
        float p3 = fast_exp2(s[mt][nt][3]);
        lsum[mt] += (p0 + p1) + (p2 + p3);
        union { f16x4 v4; f16x2 v2[2]; } u;
        u.v2[0] = pk_cvt(p0, p1);
        u.v2[1] = pk_cvt(p2, p3);
        pf[mt][nt] = u.v4;
      }
    }

    // O^T += V^T P^T at K=32: build 8-keys/lane P fragments via permlane32_swap
    __builtin_amdgcn_s_setprio(1);
#pragma unroll
    for (int u = 0; u < 4; u++) {
      f16x8 p8[2];
#pragma unroll
      for (int mt = 0; mt < 2; mt++) {
        union { f16x4 v; int d[2]; } X, Y;
        X.v = pf[mt][2 * u]; Y.v = pf[mt][2 * u + 1];
        int x0 = X.d[0], y0 = Y.d[0], x1 = X.d[1], y1 = Y.d[1];
        qswap32(x0, y0);   // x0 = low halves (j0,1), y0 = high halves (j4,5)
        qswap32(x1, y1);   // x1 = (j2,3),           y1 = (j6,7)
        union { int d[4]; f16x8 v; } P;
        P.d[0] = x0; P.d[1] = x1; P.d[2] = y0; P.d[3] = y1;
        p8[mt] = P.v;
      }
#pragma unroll
      for (int dt = 0; dt < 4; dt++) {
        f16x8 vf = *(const f16x8*)&Vt[buf][dt * 16 + col][u * 32 + quad * 8];
#pragma unroll
        for (int mt = 0; mt < 2; mt++)
          o_acc[mt][dt] = __builtin_amdgcn_mfma_f32_16x16x32_f16(vf, p8[mt], o_acc[mt][dt], 0, 0, 0);
      }
    }
    __builtin_amdgcn_s_setprio(0);

    // write prefetched tile into the other buffer; single barrier per iter
    if (j + 1 < 32) {
      const int nb = buf ^ 1;
#pragma unroll
      for (int i = 0; i < 4; i++)
        *(f16x8*)&Ks[nb][sr + 32 * i][sc] = kreg[i];
#pragma unroll
      for (int it = 0; it < 4; it++) {
        f16x4 lo, hi;
#pragma unroll
        for (int u = 0; u < 4; u++) { lo[u] = vreg[it][u]; hi[u] = vreg[it][u + 4]; }
        *(f16x4*)&Vt[nb][it * 16 + vrow][vc0] = lo;
        *(f16x4*)&Vt[nb][it * 16 + vrow][vc1] = hi;
      }
      __syncthreads();
    }
  }

  // epilogue: complete l across quads (lanes col, col+16, col+32, col+48),
  // then O /= l, write [b][t][h*64+d] fp16 (row-major 8192x512)
  const int b = bh >> 3, h = bh & 7;
#pragma unroll
  for (int mt = 0; mt < 2; mt++) {
    float l = lsum[mt];
    l += __shfl_xor(l, 16, 64);
    l += __shfl_xor(l, 32, 64);
    int row = q0 + wave * 32 + mt * 16 + col;
    float inv = 1.0f / l;
#pragma unroll
    for (int dt = 0; dt < 4; dt++) {
      f16x4 ov;
#pragma unroll
      for (int r = 0; r < 4; r++) ov[r] = (_Float16)(o_acc[mt][dt][r] * inv);
      *(f16x4*)&O[((size_t)(b * 4096 + row)) * 512 + h * 64 + dt * 16 + quad * 4] = ov;
    }
  }
}

// ---------------- output projection: out = ao @ Wo^T + bo -> fp32 ----------
// v3: 64x128 tile -> 512 blocks = 2 blocks/CU even (was 256 = 1/CU, 1 wave/
// SIMD). Reg-prefetch dbuf (1 barrier/step), XCD swizzle, swapped-operand
// MFMA -> f32x4 stores of 4 consecutive n per token.
__global__ __launch_bounds__(256, 2)
void out_gemm(const _Float16* __restrict__ X, const _Float16* __restrict__ Wo,
              const float* __restrict__ bias, float* __restrict__ out) {
  __shared__ __align__(16) _Float16 As[2][64][72];
  __shared__ __align__(16) _Float16 Bs[2][128][72];
  // XCD swizzle (bijective, 512 = 8 xcd x 64)
  const int id = blockIdx.y * 128 + blockIdx.x;
  const int xcd = id & 7, s = id >> 3;          // s in [0,64)
  const int m0 = (xcd * 16 + (s & 15)) * 64;    // m-tile in [0,128)
  const int n0 = (s >> 4) * 128;                // n-tile in [0,4)

  const int t = threadIdx.x;
  const int lane = t & 63, wave = t >> 6;
  const int quad = lane >> 4, col = lane & 15;
  const int wm = (wave & 1) * 32, wn = (wave >> 1) * 64;
  const int sr = t >> 3, sc = (t & 7) * 8;

  f32x4 acc[2][4] = {};
  f16x8 areg[2], breg[4];

#define OLOAD(K0)                                                             \
  {                                                                           \
    _Pragma("unroll") for (int i = 0; i < 2; i++)                             \
      areg[i] = *(const f16x8*)&X[(size_t)(m0 + sr + 32 * i) * 512 + (K0) + sc]; \
    _Pragma("unroll") for (int i = 0; i < 4; i++)                             \
      breg[i] = *(const f16x8*)&Wo[(size_t)(n0 + sr + 32 * i) * 512 + (K0) + sc]; \
  }

#define OSTAGE(B)                                                             \
  {                                                                           \
    _Pragma("unroll") for (int i = 0; i < 2; i++)                             \
      *(f16x8*)&As[(B)][sr + 32 * i][sc] = areg[i];                           \
    _Pragma("unroll") for (int i = 0; i < 4; i++)                             \
      *(f16x8*)&Bs[(B)][sr + 32 * i][sc] = breg[i];                           \
  }

#define OCOMP(B)                                                              \
  {                                                                           \
    _Pragma("unroll") for (int ks = 0; ks < 2; ks++) {                        \
      f16x8 a[2], b[4];                                                       \
      _Pragma("unroll") for (int i = 0; i < 2; i++)                           \
        a[i] = *(const f16x8*)&As[(B)][wm + i * 16 + col][ks * 32 + quad * 8]; \
      _Pragma("unroll") for (int i = 0; i < 4; i++)                           \
        b[i] = *(const f16x8*)&Bs[(B)][wn + i * 16 + col][ks * 32 + quad * 8]; \
      _Pragma("unroll") for (int mi = 0; mi < 2; mi++)                        \
        _Pragma("unroll") for (int ni = 0; ni < 4; ni++)                      \
          acc[mi][ni] = __builtin_amdgcn_mfma_f32_16x16x32_f16(               \
              b[ni], a[mi], acc[mi][ni], 0, 0, 0);                            \
    }                                                                         \
  }

  OLOAD(0); OSTAGE(0); OLOAD(64);
  __syncthreads();
  OCOMP(0);
  OSTAGE(1); OLOAD(128); __syncthreads(); OCOMP(1);
  OSTAGE(0); OLOAD(192); __syncthreads(); OCOMP(0);
  OSTAGE(1); OLOAD(256); __syncthreads(); OCOMP(1);
  OSTAGE(0); OLOAD(320); __syncthreads(); OCOMP(0);
  OSTAGE(1); OLOAD(384); __syncthreads(); OCOMP(1);
  OSTAGE(0); OLOAD(448); __syncthreads(); OCOMP(0);
  OSTAGE(1); __syncthreads(); OCOMP(1);
#undef OLOAD
#undef OSTAGE
#undef OCOMP

  // swapped layout: acc[mi][ni][r] = out[m0+wm+mi*16+col][n0+wn+ni*16+quad*4+r]
#pragma unroll
  for (int ni = 0; ni < 4; ni++) {
    int nb = n0 + wn + ni * 16 + quad * 4;
    f32x4 bb = *(const f32x4*)&bias[nb];
#pragma unroll
    for (int mi = 0; mi < 2; mi++) {
      int m = m0 + wm + mi * 16 + col;
      f32x4 ov;
#pragma unroll
      for (int r = 0; r < 4; r++) ov[r] = acc[mi][ni][r] + bb[r];
      *(f32x4*)&out[(size_t)m * 512 + nb] = ov;
    }
  }
}

extern "C" void kernel_launch(void* const* d_in, const int* in_sizes, int n_in,
                              void* d_out, int out_size, void* d_ws, size_t ws_size,
                              hipStream_t stream) {
  const float* x  = (const float*)d_in[0];
  const float* Wq = (const float*)d_in[1];
  const float* bq = (const float*)d_in[2];
  const float* Wk = (const float*)d_in[3];
  const float* bk = (const float*)d_in[4];
  const float* Wv = (const float*)d_in[5];
  const float* bv = (const float*)d_in[6];
  const float* Wo = (const float*)d_in[7];
  const float* bo = (const float*)d_in[8];

  char* ws = (char*)d_ws;
  _Float16* xf  = (_Float16*)(ws);                 //  8 MiB: x as f16 (dead after qkv)
  _Float16* wf  = (_Float16*)(ws + (8u << 20));    //  2 MiB: Wq,Wk,Wv,Wo f16
  _Float16* qkv = (_Float16*)(ws + (10u << 20));   // 24 MiB: Q,K [bh][t][d]; V [bh][d][t]
  _Float16* ao  = (_Float16*)(ws);                 //  8 MiB: attn out (reuses xf)

  cvt_all<<<2560, 256, 0, stream>>>(x, Wq, Wk, Wv, Wo, xf, wf);

  qkv_gemm<<<dim3(64, 4, 3), 256, 0, stream>>>(xf, wf, bq, bk, bv, qkv);

  attn_kernel<<<dim3(32, 16), 256, 0, stream>>>(qkv, qkv + 4194304,
                                                qkv + 2 * 4194304, ao);

  out_gemm<<<dim3(128, 4), 256, 0, stream>>>(ao, wf + 3 * 262144, bo,
                                             (float*)d_out);
}

// Round 11
// 193.978 us; speedup vs baseline: 1.0433x; 1.0433x over previous
//
#include <hip/hip_runtime.h>

typedef _Float16 f16x8 __attribute__((ext_vector_type(8)));
typedef _Float16 f16x4 __attribute__((ext_vector_type(4)));
typedef _Float16 f16x2 __attribute__((ext_vector_type(2)));
typedef __fp16 hf16x2 __attribute__((ext_vector_type(2)));
typedef float f32x4 __attribute__((ext_vector_type(4)));

__device__ __forceinline__ float fast_exp2(float x) {
#if __has_builtin(__builtin_amdgcn_exp2f)
  return __builtin_amdgcn_exp2f(x);
#else
  return exp2f(x);
#endif
}

__device__ __forceinline__ f16x2 pk_cvt(float a, float b) {
#if __has_builtin(__builtin_amdgcn_cvt_pkrtz)
  union { hf16x2 h; f16x2 f; } u;
  u.h = __builtin_amdgcn_cvt_pkrtz(a, b);
  return u.f;
#else
  f16x2 r; r[0] = (_Float16)a; r[1] = (_Float16)b; return r;
#endif
}

// v_permlane32_swap_b32: x <- {x.lanes[0:31], y.lanes[0:31]},
//                        y <- {x.lanes[32:63], y.lanes[32:63]}
__device__ __forceinline__ void qswap32(int& x, int& y) {
  asm("v_permlane32_swap_b32 %0, %1" : "+v"(x), "+v"(y));
}

// key-index involution: swap bits 2 and 3 (sigma == pi, self-inverse)
__device__ __forceinline__ int swz23(int c) {
  return (c & ~12) | ((c & 4) << 1) | ((c & 8) >> 1);
}

// ---------------- fused f32 -> f16 convert prepass ----------------
__global__ void cvt_all(const float* __restrict__ x,
                        const float* __restrict__ Wq, const float* __restrict__ Wk,
                        const float* __restrict__ Wv, const float* __restrict__ Wo,
                        _Float16* __restrict__ xf, _Float16* __restrict__ wf) {
  int g = blockIdx.x * blockDim.x + threadIdx.x;
  const float* src;
  _Float16* dst;
  if (g < 524288) {
    src = x + (size_t)g * 8;
    dst = xf + (size_t)g * 8;
  } else {
    int g2 = g - 524288;
    int z = g2 >> 15, off = g2 & 32767;
    const float* W = (z == 0) ? Wq : (z == 1) ? Wk : (z == 2) ? Wv : Wo;
    src = W + (size_t)off * 8;
    dst = wf + (size_t)z * 262144 + (size_t)off * 8;
  }
  f32x4 a = *(const f32x4*)src;
  f32x4 b = *(const f32x4*)(src + 4);
  f16x8 o;
  o[0] = (_Float16)a[0]; o[1] = (_Float16)a[1];
  o[2] = (_Float16)a[2]; o[3] = (_Float16)a[3];
  o[4] = (_Float16)b[0]; o[5] = (_Float16)b[1];
  o[6] = (_Float16)b[2]; o[7] = (_Float16)b[3];
  *(f16x8*)dst = o;
}

// ---------------- fused QKV projection: y = x @ W^T + b ----------------
// R9-verified: BK=64 reg-prefetch double-buffer (1 barrier/k-step, 16 MFMAs
// per barrier), XCD swizzle (X panel per XCD L2-hot, reused 12x).
// Q,K (z!=2): swapped-operand MFMA -> f16x4 stores of 4 consecutive d.
// V (z==2): normal order, written TRANSPOSED [bh][d][t].
__global__ __launch_bounds__(256, 2)
void qkv_gemm(const _Float16* __restrict__ X, const _Float16* __restrict__ Wf,
              const float* __restrict__ bq, const float* __restrict__ bk,
              const float* __restrict__ bv, _Float16* __restrict__ dst3) {
  __shared__ __align__(16) _Float16 As[2][128][72];
  __shared__ __align__(16) _Float16 Bs[2][128][72];
  // XCD swizzle (bijective, 768 = 8 xcd x 96)
  const int id = (blockIdx.z * 4 + blockIdx.y) * 64 + blockIdx.x;
  const int xcd = id & 7, s = id >> 3;          // s in [0,96)
  const int m0 = (xcd * 8 + (s & 7)) * 128;     // m-tile in [0,64)
  const int yz = s >> 3;                        // [0,12)
  const int n0 = (yz & 3) * 128;
  const int z = yz >> 2;
  const _Float16* Wz = Wf + (size_t)z * 262144;
  const float* bias = (z == 0) ? bq : (z == 1 ? bk : bv);
  _Float16* dst = dst3 + (size_t)z * 4194304;
  const float scale = (z == 0) ? 0.18033688011112042f : 1.0f;

  const int t = threadIdx.x;
  const int lane = t & 63, wave = t >> 6;
  const int quad = lane >> 4, col = lane & 15;
  const int wm = (wave & 1) * 64, wn = (wave >> 1) * 64;
  const int sr = (t * 8) >> 6, sc = (t * 8) & 63;   // staging row/col (per i: +32)

  f32x4 acc[4][4] = {};
  f16x8 areg[4], breg[4];

#define GLOAD(K0)                                                             \
  {                                                                           \
    _Pragma("unroll") for (int i = 0; i < 4; i++) {                           \
      areg[i] = *(const f16x8*)&X[(size_t)(m0 + sr + 32 * i) * 512 + (K0) + sc]; \
      breg[i] = *(const f16x8*)&Wz[(size_t)(n0 + sr + 32 * i) * 512 + (K0) + sc]; \
    }                                                                         \
  }

#define GSTAGE(B)                                                             \
  {                                                                           \
    _Pragma("unroll") for (int i = 0; i < 4; i++) {                           \
      *(f16x8*)&As[(B)][sr + 32 * i][sc] = areg[i];                           \
      *(f16x8*)&Bs[(B)][sr + 32 * i][sc] = breg[i];                           \
    }                                                                         \
  }

#define GCOMP_QK(B)                                                           \
  {                                                                           \
    _Pragma("unroll") for (int ks = 0; ks < 2; ks++) {                        \
      f16x8 a[4], b[4];                                                       \
      _Pragma("unroll") for (int i = 0; i < 4; i++) {                         \
        a[i] = *(const f16x8*)&As[(B)][wm + i * 16 + col][ks * 32 + quad * 8]; \
        b[i] = *(const f16x8*)&Bs[(B)][wn + i * 16 + col][ks * 32 + quad * 8]; \
      }                                                                       \
      _Pragma("unroll") for (int mi = 0; mi < 4; mi++)                        \
        _Pragma("unroll") for (int ni = 0; ni < 4; ni++)                      \
          acc[mi][ni] = __builtin_amdgcn_mfma_f32_16x16x32_f16(               \
              b[ni], a[mi], acc[mi][ni], 0, 0, 0);                            \
    }                                                                         \
  }

#define GCOMP_V(B)                                                            \
  {                                                                           \
    _Pragma("unroll") for (int ks = 0; ks < 2; ks++) {                        \
      f16x8 a[4], b[4];                                                       \
      _Pragma("unroll") for (int i = 0; i < 4; i++) {                         \
        a[i] = *(const f16x8*)&As[(B)][wm + i * 16 + col][ks * 32 + quad * 8]; \
        b[i] = *(const f16x8*)&Bs[(B)][wn + i * 16 + col][ks * 32 + quad * 8]; \
      }                                                                       \
      _Pragma("unroll") for (int mi = 0; mi < 4; mi++)                        \
        _Pragma("unroll") for (int ni = 0; ni < 4; ni++)                      \
          acc[mi][ni] = __builtin_amdgcn_mfma_f32_16x16x32_f16(               \
              a[mi], b[ni], acc[mi][ni], 0, 0, 0);                            \
    }                                                                         \
  }

  if (z != 2) {
    GLOAD(0); GSTAGE(0); GLOAD(64);
    __syncthreads();
    GCOMP_QK(0);
    GSTAGE(1); GLOAD(128); __syncthreads(); GCOMP_QK(1);
    GSTAGE(0); GLOAD(192); __syncthreads(); GCOMP_QK(0);
    GSTAGE(1); GLOAD(256); __syncthreads(); GCOMP_QK(1);
    GSTAGE(0); GLOAD(320); __syncthreads(); GCOMP_QK(0);
    GSTAGE(1); GLOAD(384); __syncthreads(); GCOMP_QK(1);
    GSTAGE(0); GLOAD(448); __syncthreads(); GCOMP_QK(0);
    GSTAGE(1); __syncthreads(); GCOMP_QK(1);
    // Q,K: [bh][t][d], f16x4 of 4 consecutive d per token
#pragma unroll
    for (int ni = 0; ni < 4; ni++) {
      int nb = n0 + wn + ni * 16 + quad * 4;   // 4 consecutive features
      int h = nb >> 6, d0 = nb & 63;
      f32x4 bb = *(const f32x4*)&bias[nb];
#pragma unroll
      for (int mi = 0; mi < 4; mi++) {
        int m = m0 + wm + mi * 16 + col;
        int b = m >> 12, tt = m & 4095;
        f16x4 ov;
#pragma unroll
        for (int r = 0; r < 4; r++)
          ov[r] = (_Float16)((acc[mi][ni][r] + bb[r]) * scale);
        *(f16x4*)&dst[((size_t)(b * 8 + h) * 4096 + tt) * 64 + d0] = ov;
      }
    }
  } else {
    GLOAD(0); GSTAGE(0); GLOAD(64);
    __syncthreads();
    GCOMP_V(0);
    GSTAGE(1); GLOAD(128); __syncthreads(); GCOMP_V(1);
    GSTAGE(0); GLOAD(192); __syncthreads(); GCOMP_V(0);
    GSTAGE(1); GLOAD(256); __syncthreads(); GCOMP_V(1);
    GSTAGE(0); GLOAD(320); __syncthreads(); GCOMP_V(0);
    GSTAGE(1); GLOAD(384); __syncthreads(); GCOMP_V(1);
    GSTAGE(0); GLOAD(448); __syncthreads(); GCOMP_V(0);
    GSTAGE(1); __syncthreads(); GCOMP_V(1);
    // V: [bh][d][t] layout, vectorized f16x4 along t
#pragma unroll
    for (int ni = 0; ni < 4; ni++) {
      int n = n0 + wn + ni * 16 + col;
      float bv_ = bias[n];
      int h = n >> 6, d = n & 63;
#pragma unroll
      for (int mi = 0; mi < 4; mi++) {
        int m = m0 + wm + mi * 16 + quad * 4;
        int b = m >> 12, tt = m & 4095;
        f16x4 ov;
#pragma unroll
        for (int r = 0; r < 4; r++) ov[r] = (_Float16)(acc[mi][ni][r] + bv_);
        *(f16x4*)&dst[((size_t)((b * 8 + h) * 64 + d)) * 4096 + tt] = ov;
      }
    }
  }
#undef GLOAD
#undef GSTAGE
#undef GCOMP_QK
#undef GCOMP_V
}

// ---------------- flash attention (R6-verified, ~92-94 us) -----------------
// 128-key KV tiles, 32 q/wave, reg-prefetch dbuf, XCD swizzle (2 bh/XCD),
// PV at K=32 via permlane32_swap + bit2<->3 V swizzle, lsum on VALU,
// setprio around MFMA clusters.
__global__ __launch_bounds__(256, 2)
void attn_kernel(const _Float16* __restrict__ Q, const _Float16* __restrict__ K,
                 const _Float16* __restrict__ V, _Float16* __restrict__ O) {
  __shared__ __align__(16) _Float16 Ks[2][128][72];
  __shared__ __align__(16) _Float16 Vt[2][64][136]; // pitch 136: 16B-aligned rows

  const int t = threadIdx.x;
  const int lane = t & 63, wave = t >> 6;
  const int quad = lane >> 4, col = lane & 15;
  // XCD swizzle: id%8 = XCD (round-robin dispatch); give each XCD 2 whole bh
  const int id = blockIdx.y * 32 + blockIdx.x;
  const int xcd = id & 7, slot = id >> 3;
  const int bh = xcd * 2 + (slot >> 5);
  const int q0 = (slot & 31) * 128;
  const _Float16* Qb = Q + (size_t)bh * 4096 * 64;
  const _Float16* Kbh = K + (size_t)bh * 4096 * 64;
  const _Float16* Vg = V + (size_t)bh * 64 * 4096;   // [d][t]

  // staging coords
  const int sr = (t * 8) >> 6, sc = (t * 8) & 63;    // K rows: r = sr + 32*i
  const int vrow = t >> 4, vcol = (t & 15) * 8;      // V^T rows: d = vrow + 16*it
  const int vc0 = swz23(vcol);                       // sigma(vcol)
  const int vc1 = swz23(vcol + 4);                   // sigma(vcol+4)

  // Q as B-fragment: B[n=query=mt*16+col][k=d=ks*32+quad*8+j]
  f16x8 qf[2][2];
#pragma unroll
  for (int mt = 0; mt < 2; mt++)
#pragma unroll
    for (int ks = 0; ks < 2; ks++)
      qf[mt][ks] = *(const f16x8*)&Qb[(size_t)(q0 + wave * 32 + mt * 16 + col) * 64 +
                                      ks * 32 + quad * 8];

  const f32x4 fz = {0.f, 0.f, 0.f, 0.f};

  f16x8 kreg[4], vreg[4];
  // prologue: load tile 0
#pragma unroll
  for (int i = 0; i < 4; i++)
    kreg[i] = *(const f16x8*)&Kbh[(size_t)(sr + 32 * i) * 64 + sc];
#pragma unroll
  for (int it = 0; it < 4; it++)
    vreg[it] = *(const f16x8*)&Vg[(size_t)(it * 16 + vrow) * 4096 + vcol];
#pragma unroll
  for (int i = 0; i < 4; i++)
    *(f16x8*)&Ks[0][sr + 32 * i][sc] = kreg[i];
#pragma unroll
  for (int it = 0; it < 4; it++) {
    f16x4 lo, hi;
#pragma unroll
    for (int u = 0; u < 4; u++) { lo[u] = vreg[it][u]; hi[u] = vreg[it][u + 4]; }
    *(f16x4*)&Vt[0][it * 16 + vrow][vc0] = lo;
    *(f16x4*)&Vt[0][it * 16 + vrow][vc1] = hi;
  }
  __syncthreads();

  // o_acc[mt][dt][r] = O^T[d=dt*16+quad*4+r][query=mt*16+col]
  f32x4 o_acc[2][4] = {};
  // per-lane partial row-sum of P for query=col, keys {nt*16+quad*4+r, all nt,j}
  float lsum[2] = {0.f, 0.f};

  for (int j = 0; j < 32; j++) {
    const int buf = j & 1;
    // prefetch tile j+1 into registers (latency hidden behind compute)
    if (j + 1 < 32) {
      const _Float16* Kb = Kbh + (size_t)(j + 1) * 128 * 64;
#pragma unroll
      for (int i = 0; i < 4; i++)
        kreg[i] = *(const f16x8*)&Kb[(size_t)(sr + 32 * i) * 64 + sc];
#pragma unroll
      for (int it = 0; it < 4; it++)
        vreg[it] = *(const f16x8*)&Vg[(size_t)(it * 16 + vrow) * 4096 +
                                      (j + 1) * 128 + vcol];
    }

    // S^T[key][query]: s[mt][nt][r] = S[q=mt*16+col][key=nt*16+quad*4+r]
    f32x4 s[2][8];
    __builtin_amdgcn_s_setprio(1);
#pragma unroll
    for (int nt = 0; nt < 8; nt++) {
      f16x8 kf = *(const f16x8*)&Ks[buf][nt * 16 + col][quad * 8];
#pragma unroll
      for (int mt = 0; mt < 2; mt++)
        s[mt][nt] = __builtin_amdgcn_mfma_f32_16x16x32_f16(kf, qf[mt][0], fz, 0, 0, 0);
    }
#pragma unroll
    for (int nt = 0; nt < 8; nt++) {
      f16x8 kf = *(const f16x8*)&Ks[buf][nt * 16 + col][32 + quad * 8];
#pragma unroll
      for (int mt = 0; mt < 2; mt++)
        s[mt][nt] = __builtin_amdgcn_mfma_f32_16x16x32_f16(kf, qf[mt][1], s[mt][nt], 0, 0, 0);
    }
    __builtin_amdgcn_s_setprio(0);

    // P = exp2(S^T): bare v_exp_f32 + packed f32->f16; l-accum on VALU pipe
    f16x4 pf[2][8];
#pragma unroll
    for (int mt = 0; mt < 2; mt++) {
#pragma unroll
      for (int nt = 0; nt < 8; nt++) {
        float p0 = fast_exp2(s[mt][nt][0]);
        float p1 = fast_exp2(s[mt][nt][1]);
        float p2 = fast_exp2(s[mt][nt][2]);
        float p3 = fast_exp2(s[mt][nt][3]);
        lsum[mt] += (p0 + p1) + (p2 + p3);
        union { f16x4 v4; f16x2 v2[2]; } u;
        u.v2[0] = pk_cvt(p0, p1);
        u.v2[1] = pk_cvt(p2, p3);
        pf[mt][nt] = u.v4;
      }
    }

    // O^T += V^T P^T at K=32: build 8-keys/lane P fragments via permlane32_swap
    __builtin_amdgcn_s_setprio(1);
#pragma unroll
    for (int u = 0; u < 4; u++) {
      f16x8 p8[2];
#pragma unroll
      for (int mt = 0; mt < 2; mt++) {
        union { f16x4 v; int d[2]; } X, Y;
        X.v = pf[mt][2 * u]; Y.v = pf[mt][2 * u + 1];
        int x0 = X.d[0], y0 = Y.d[0], x1 = X.d[1], y1 = Y.d[1];
        qswap32(x0, y0);   // x0 = low halves (j0,1), y0 = high halves (j4,5)
        qswap32(x1, y1);   // x1 = (j2,3),           y1 = (j6,7)
        union { int d[4]; f16x8 v; } P;
        P.d[0] = x0; P.d[1] = x1; P.d[2] = y0; P.d[3] = y1;
        p8[mt] = P.v;
      }
#pragma unroll
      for (int dt = 0; dt < 4; dt++) {
        f16x8 vf = *(const f16x8*)&Vt[buf][dt * 16 + col][u * 32 + quad * 8];
#pragma unroll
        for (int mt = 0; mt < 2; mt++)
          o_acc[mt][dt] = __builtin_amdgcn_mfma_f32_16x16x32_f16(vf, p8[mt], o_acc[mt][dt], 0, 0, 0);
      }
    }
    __builtin_amdgcn_s_setprio(0);

    // write prefetched tile into the other buffer; single barrier per iter
    if (j + 1 < 32) {
      const int nb = buf ^ 1;
#pragma unroll
      for (int i = 0; i < 4; i++)
        *(f16x8*)&Ks[nb][sr + 32 * i][sc] = kreg[i];
#pragma unroll
      for (int it = 0; it < 4; it++) {
        f16x4 lo, hi;
#pragma unroll
        for (int u = 0; u < 4; u++) { lo[u] = vreg[it][u]; hi[u] = vreg[it][u + 4]; }
        *(f16x4*)&Vt[nb][it * 16 + vrow][vc0] = lo;
        *(f16x4*)&Vt[nb][it * 16 + vrow][vc1] = hi;
      }
      __syncthreads();
    }
  }

  // epilogue: complete l across quads (lanes col, col+16, col+32, col+48),
  // then O /= l, write [b][t][h*64+d] fp16 (row-major 8192x512)
  const int b = bh >> 3, h = bh & 7;
#pragma unroll
  for (int mt = 0; mt < 2; mt++) {
    float l = lsum[mt];
    l += __shfl_xor(l, 16, 64);
    l += __shfl_xor(l, 32, 64);
    int row = q0 + wave * 32 + mt * 16 + col;
    float inv = 1.0f / l;
#pragma unroll
    for (int dt = 0; dt < 4; dt++) {
      f16x4 ov;
#pragma unroll
      for (int r = 0; r < 4; r++) ov[r] = (_Float16)(o_acc[mt][dt][r] * inv);
      *(f16x4*)&O[((size_t)(b * 4096 + row)) * 512 + h * 64 + dt * 16 + quad * 4] = ov;
    }
  }
}

// ---------------- output projection: out = ao @ Wo^T + bo -> fp32 ----------
// v3 (kept from R10): 64x128 tile -> 512 blocks = 2 blocks/CU even (was 256
// = 1/CU, 1 wave/SIMD). Reg-prefetch dbuf (1 barrier/step, 16 MFMAs each),
// XCD swizzle, swapped-operand MFMA -> f32x4 stores.
__global__ __launch_bounds__(256, 2)
void out_gemm(const _Float16* __restrict__ X, const _Float16* __restrict__ Wo,
              const float* __restrict__ bias, float* __restrict__ out) {
  __shared__ __align__(16) _Float16 As[2][64][72];
  __shared__ __align__(16) _Float16 Bs[2][128][72];
  // XCD swizzle (bijective, 512 = 8 xcd x 64)
  const int id = blockIdx.y * 128 + blockIdx.x;
  const int xcd = id & 7, s = id >> 3;          // s in [0,64)
  const int m0 = (xcd * 16 + (s & 15)) * 64;    // m-tile in [0,128)
  const int n0 = (s >> 4) * 128;                // n-tile in [0,4)

  const int t = threadIdx.x;
  const int lane = t & 63, wave = t >> 6;
  const int quad = lane >> 4, col = lane & 15;
  const int wm = (wave & 1) * 32, wn = (wave >> 1) * 64;
  const int sr = t >> 3, sc = (t & 7) * 8;

  f32x4 acc[2][4] = {};
  f16x8 areg[2], breg[4];

#define OLOAD(K0)                                                             \
  {                                                                           \
    _Pragma("unroll") for (int i = 0; i < 2; i++)                             \
      areg[i] = *(const f16x8*)&X[(size_t)(m0 + sr + 32 * i) * 512 + (K0) + sc]; \
    _Pragma("unroll") for (int i = 0; i < 4; i++)                             \
      breg[i] = *(const f16x8*)&Wo[(size_t)(n0 + sr + 32 * i) * 512 + (K0) + sc]; \
  }

#define OSTAGE(B)                                                             \
  {                                                                           \
    _Pragma("unroll") for (int i = 0; i < 2; i++)                             \
      *(f16x8*)&As[(B)][sr + 32 * i][sc] = areg[i];                           \
    _Pragma("unroll") for (int i = 0; i < 4; i++)                             \
      *(f16x8*)&Bs[(B)][sr + 32 * i][sc] = breg[i];                           \
  }

#define OCOMP(B)                                                              \
  {                                                                           \
    _Pragma("unroll") for (int ks = 0; ks < 2; ks++) {                        \
      f16x8 a[2], b[4];                                                       \
      _Pragma("unroll") for (int i = 0; i < 2; i++)                           \
        a[i] = *(const f16x8*)&As[(B)][wm + i * 16 + col][ks * 32 + quad * 8]; \
      _Pragma("unroll") for (int i = 0; i < 4; i++)                           \
        b[i] = *(const f16x8*)&Bs[(B)][wn + i * 16 + col][ks * 32 + quad * 8]; \
      _Pragma("unroll") for (int mi = 0; mi < 2; mi++)                        \
        _Pragma("unroll") for (int ni = 0; ni < 4; ni++)                      \
          acc[mi][ni] = __builtin_amdgcn_mfma_f32_16x16x32_f16(               \
              b[ni], a[mi], acc[mi][ni], 0, 0, 0);                            \
    }                                                                         \
  }

  OLOAD(0); OSTAGE(0); OLOAD(64);
  __syncthreads();
  OCOMP(0);
  OSTAGE(1); OLOAD(128); __syncthreads(); OCOMP(1);
  OSTAGE(0); OLOAD(192); __syncthreads(); OCOMP(0);
  OSTAGE(1); OLOAD(256); __syncthreads(); OCOMP(1);
  OSTAGE(0); OLOAD(320); __syncthreads(); OCOMP(0);
  OSTAGE(1); OLOAD(384); __syncthreads(); OCOMP(1);
  OSTAGE(0); OLOAD(448); __syncthreads(); OCOMP(0);
  OSTAGE(1); __syncthreads(); OCOMP(1);
#undef OLOAD
#undef OSTAGE
#undef OCOMP

  // swapped layout: acc[mi][ni][r] = out[m0+wm+mi*16+col][n0+wn+ni*16+quad*4+r]
#pragma unroll
  for (int ni = 0; ni < 4; ni++) {
    int nb = n0 + wn + ni * 16 + quad * 4;
    f32x4 bb = *(const f32x4*)&bias[nb];
#pragma unroll
    for (int mi = 0; mi < 2; mi++) {
      int m = m0 + wm + mi * 16 + col;
      f32x4 ov;
#pragma unroll
      for (int r = 0; r < 4; r++) ov[r] = acc[mi][ni][r] + bb[r];
      *(f32x4*)&out[(size_t)m * 512 + nb] = ov;
    }
  }
}

extern "C" void kernel_launch(void* const* d_in, const int* in_sizes, int n_in,
                              void* d_out, int out_size, void* d_ws, size_t ws_size,
                              hipStream_t stream) {
  const float* x  = (const float*)d_in[0];
  const float* Wq = (const float*)d_in[1];
  const float* bq = (const float*)d_in[2];
  const float* Wk = (const float*)d_in[3];
  const float* bk = (const float*)d_in[4];
  const float* Wv = (const float*)d_in[5];
  const float* bv = (const float*)d_in[6];
  const float* Wo = (const float*)d_in[7];
  const float* bo = (const float*)d_in[8];

  char* ws = (char*)d_ws;
  _Float16* xf  = (_Float16*)(ws);                 //  8 MiB: x as f16 (dead after qkv)
  _Float16* wf  = (_Float16*)(ws + (8u << 20));    //  2 MiB: Wq,Wk,Wv,Wo f16
  _Float16* qkv = (_Float16*)(ws + (10u << 20));   // 24 MiB: Q,K [bh][t][d]; V [bh][d][t]
  _Float16* ao  = (_Float16*)(ws);                 //  8 MiB: attn out (reuses xf)

  cvt_all<<<2560, 256, 0, stream>>>(x, Wq, Wk, Wv, Wo, xf, wf);

  qkv_gemm<<<dim3(64, 4, 3), 256, 0, stream>>>(xf, wf, bq, bk, bv, qkv);

  attn_kernel<<<dim3(32, 16), 256, 0, stream>>>(qkv, qkv + 4194304,
                                                qkv + 2 * 4194304, ao);

  out_gemm<<<dim3(128, 4), 256, 0, stream>>>(ao, wf + 3 * 262144, bo,
                                             (float*)d_out);
}

// Round 13
// 191.287 us; speedup vs baseline: 1.0580x; 1.0141x over previous
//
#include <hip/hip_runtime.h>

typedef _Float16 f16x8 __attribute__((ext_vector_type(8)));
typedef _Float16 f16x4 __attribute__((ext_vector_type(4)));
typedef _Float16 f16x2 __attribute__((ext_vector_type(2)));
typedef __fp16 hf16x2 __attribute__((ext_vector_type(2)));
typedef float f32x4 __attribute__((ext_vector_type(4)));

__device__ __forceinline__ float fast_exp2(float x) {
#if __has_builtin(__builtin_amdgcn_exp2f)
  return __builtin_amdgcn_exp2f(x);
#else
  return exp2f(x);
#endif
}

__device__ __forceinline__ f16x2 pk_cvt(float a, float b) {
#if __has_builtin(__builtin_amdgcn_cvt_pkrtz)
  union { hf16x2 h; f16x2 f; } u;
  u.h = __builtin_amdgcn_cvt_pkrtz(a, b);
  return u.f;
#else
  f16x2 r; r[0] = (_Float16)a; r[1] = (_Float16)b; return r;
#endif
}

// v_permlane32_swap_b32: x <- {x.lanes[0:31], y.lanes[0:31]},
//                        y <- {x.lanes[32:63], y.lanes[32:63]}
__device__ __forceinline__ void qswap32(int& x, int& y) {
  asm("v_permlane32_swap_b32 %0, %1" : "+v"(x), "+v"(y));
}

// key-index involution: swap bits 2 and 3 (sigma == pi, self-inverse)
__device__ __forceinline__ int swz23(int c) {
  return (c & ~12) | ((c & 4) << 1) | ((c & 8) >> 1);
}

// ---------------- fused f32 -> f16 convert prepass ----------------
__global__ void cvt_all(const float* __restrict__ x,
                        const float* __restrict__ Wq, const float* __restrict__ Wk,
                        const float* __restrict__ Wv, const float* __restrict__ Wo,
                        _Float16* __restrict__ xf, _Float16* __restrict__ wf) {
  int g = blockIdx.x * blockDim.x + threadIdx.x;
  const float* src;
  _Float16* dst;
  if (g < 524288) {
    src = x + (size_t)g * 8;
    dst = xf + (size_t)g * 8;
  } else {
    int g2 = g - 524288;
    int z = g2 >> 15, off = g2 & 32767;
    const float* W = (z == 0) ? Wq : (z == 1) ? Wk : (z == 2) ? Wv : Wo;
    src = W + (size_t)off * 8;
    dst = wf + (size_t)z * 262144 + (size_t)off * 8;
  }
  f32x4 a = *(const f32x4*)src;
  f32x4 b = *(const f32x4*)(src + 4);
  f16x8 o;
  o[0] = (_Float16)a[0]; o[1] = (_Float16)a[1];
  o[2] = (_Float16)a[2]; o[3] = (_Float16)a[3];
  o[4] = (_Float16)b[0]; o[5] = (_Float16)b[1];
  o[6] = (_Float16)b[2]; o[7] = (_Float16)b[3];
  *(f16x8*)dst = o;
}

// ---------------- fused QKV projection: y = x @ W^T + b ----------------
// R9-verified: BK=64 reg-prefetch double-buffer (1 barrier/k-step, 16 MFMAs
// per barrier), XCD swizzle (X panel per XCD L2-hot, reused 12x).
// Q,K (z!=2): swapped-operand MFMA -> f16x4 stores of 4 consecutive d.
// V (z==2): normal order, written TRANSPOSED [bh][d][t] with the key-index
// bits-2<->3 involution PRE-APPLIED to t (V'[d][c] = V[d][sigma(c)]) so attn
// can stage straight f16x8 rows (no LDS-side swizzle, fewer bank conflicts).
__global__ __launch_bounds__(256, 2)
void qkv_gemm(const _Float16* __restrict__ X, const _Float16* __restrict__ Wf,
              const float* __restrict__ bq, const float* __restrict__ bk,
              const float* __restrict__ bv, _Float16* __restrict__ dst3) {
  __shared__ __align__(16) _Float16 As[2][128][72];
  __shared__ __align__(16) _Float16 Bs[2][128][72];
  // XCD swizzle (bijective, 768 = 8 xcd x 96)
  const int id = (blockIdx.z * 4 + blockIdx.y) * 64 + blockIdx.x;
  const int xcd = id & 7, s = id >> 3;          // s in [0,96)
  const int m0 = (xcd * 8 + (s & 7)) * 128;     // m-tile in [0,64)
  const int yz = s >> 3;                        // [0,12)
  const int n0 = (yz & 3) * 128;
  const int z = yz >> 2;
  const _Float16* Wz = Wf + (size_t)z * 262144;
  const float* bias = (z == 0) ? bq : (z == 1 ? bk : bv);
  _Float16* dst = dst3 + (size_t)z * 4194304;
  const float scale = (z == 0) ? 0.18033688011112042f : 1.0f;

  const int t = threadIdx.x;
  const int lane = t & 63, wave = t >> 6;
  const int quad = lane >> 4, col = lane & 15;
  const int wm = (wave & 1) * 64, wn = (wave >> 1) * 64;
  const int sr = (t * 8) >> 6, sc = (t * 8) & 63;   // staging row/col (per i: +32)

  f32x4 acc[4][4] = {};
  f16x8 areg[4], breg[4];

#define GLOAD(K0)                                                             \
  {                                                                           \
    _Pragma("unroll") for (int i = 0; i < 4; i++) {                           \
      areg[i] = *(const f16x8*)&X[(size_t)(m0 + sr + 32 * i) * 512 + (K0) + sc]; \
      breg[i] = *(const f16x8*)&Wz[(size_t)(n0 + sr + 32 * i) * 512 + (K0) + sc]; \
    }                                                                         \
  }

#define GSTAGE(B)                                                             \
  {                                                                           \
    _Pragma("unroll") for (int i = 0; i < 4; i++) {                           \
      *(f16x8*)&As[(B)][sr + 32 * i][sc] = areg[i];                           \
      *(f16x8*)&Bs[(B)][sr + 32 * i][sc] = breg[i];                           \
    }                                                                         \
  }

#define GCOMP_QK(B)                                                           \
  {                                                                           \
    _Pragma("unroll") for (int ks = 0; ks < 2; ks++) {                        \
      f16x8 a[4], b[4];                                                       \
      _Pragma("unroll") for (int i = 0; i < 4; i++) {                         \
        a[i] = *(const f16x8*)&As[(B)][wm + i * 16 + col][ks * 32 + quad * 8]; \
        b[i] = *(const f16x8*)&Bs[(B)][wn + i * 16 + col][ks * 32 + quad * 8]; \
      }                                                                       \
      _Pragma("unroll") for (int mi = 0; mi < 4; mi++)                        \
        _Pragma("unroll") for (int ni = 0; ni < 4; ni++)                      \
          acc[mi][ni] = __builtin_amdgcn_mfma_f32_16x16x32_f16(               \
              b[ni], a[mi], acc[mi][ni], 0, 0, 0);                            \
    }                                                                         \
  }

#define GCOMP_V(B)                                                            \
  {                                                                           \
    _Pragma("unroll") for (int ks = 0; ks < 2; ks++) {                        \
      f16x8 a[4], b[4];                                                       \
      _Pragma("unroll") for (int i = 0; i < 4; i++) {                         \
        a[i] = *(const f16x8*)&As[(B)][wm + i * 16 + col][ks * 32 + quad * 8]; \
        b[i] = *(const f16x8*)&Bs[(B)][wn + i * 16 + col][ks * 32 + quad * 8]; \
      }                                                                       \
      _Pragma("unroll") for (int mi = 0; mi < 4; mi++)                        \
        _Pragma("unroll") for (int ni = 0; ni < 4; ni++)                      \
          acc[mi][ni] = __builtin_amdgcn_mfma_f32_16x16x32_f16(               \
              a[mi], b[ni], acc[mi][ni], 0, 0, 0);                            \
    }                                                                         \
  }

  if (z != 2) {
    GLOAD(0); GSTAGE(0); GLOAD(64);
    __syncthreads();
    GCOMP_QK(0);
    GSTAGE(1); GLOAD(128); __syncthreads(); GCOMP_QK(1);
    GSTAGE(0); GLOAD(192); __syncthreads(); GCOMP_QK(0);
    GSTAGE(1); GLOAD(256); __syncthreads(); GCOMP_QK(1);
    GSTAGE(0); GLOAD(320); __syncthreads(); GCOMP_QK(0);
    GSTAGE(1); GLOAD(384); __syncthreads(); GCOMP_QK(1);
    GSTAGE(0); GLOAD(448); __syncthreads(); GCOMP_QK(0);
    GSTAGE(1); __syncthreads(); GCOMP_QK(1);
    // Q,K: [bh][t][d], f16x4 of 4 consecutive d per token
#pragma unroll
    for (int ni = 0; ni < 4; ni++) {
      int nb = n0 + wn + ni * 16 + quad * 4;   // 4 consecutive features
      int h = nb >> 6, d0 = nb & 63;
      f32x4 bb = *(const f32x4*)&bias[nb];
#pragma unroll
      for (int mi = 0; mi < 4; mi++) {
        int m = m0 + wm + mi * 16 + col;
        int b = m >> 12, tt = m & 4095;
        f16x4 ov;
#pragma unroll
        for (int r = 0; r < 4; r++)
          ov[r] = (_Float16)((acc[mi][ni][r] + bb[r]) * scale);
        *(f16x4*)&dst[((size_t)(b * 8 + h) * 4096 + tt) * 64 + d0] = ov;
      }
    }
  } else {
    GLOAD(0); GSTAGE(0); GLOAD(64);
    __syncthreads();
    GCOMP_V(0);
    GSTAGE(1); GLOAD(128); __syncthreads(); GCOMP_V(1);
    GSTAGE(0); GLOAD(192); __syncthreads(); GCOMP_V(0);
    GSTAGE(1); GLOAD(256); __syncthreads(); GCOMP_V(1);
    GSTAGE(0); GLOAD(320); __syncthreads(); GCOMP_V(0);
    GSTAGE(1); GLOAD(384); __syncthreads(); GCOMP_V(1);
    GSTAGE(0); GLOAD(448); __syncthreads(); GCOMP_V(0);
    GSTAGE(1); __syncthreads(); GCOMP_V(1);
    // V: [bh][d][t'] with t' = sigma(t) (bits 2<->3 swapped). The f16x4 block
    // tt..tt+3 is 4-aligned, so sigma maps it to the 4-aligned block at
    // sigma(tt) -- same store width, same coalescing.
#pragma unroll
    for (int ni = 0; ni < 4; ni++) {
      int n = n0 + wn + ni * 16 + col;
      float bv_ = bias[n];
      int h = n >> 6, d = n & 63;
#pragma unroll
      for (int mi = 0; mi < 4; mi++) {
        int m = m0 + wm + mi * 16 + quad * 4;
        int b = m >> 12, tt = m & 4095;
        int tts = swz23(tt);
        f16x4 ov;
#pragma unroll
        for (int r = 0; r < 4; r++) ov[r] = (_Float16)(acc[mi][ni][r] + bv_);
        *(f16x4*)&dst[((size_t)((b * 8 + h) * 64 + d)) * 4096 + tts] = ov;
      }
    }
  }
#undef GLOAD
#undef GSTAGE
#undef GCOMP_QK
#undef GCOMP_V
}

// ---------------- flash attention (R6-verified structure) ------------------
// 128-key KV tiles, 32 q/wave, reg-prefetch dbuf, XCD swizzle (2 bh/XCD),
// PV at K=32 via permlane32_swap; V arrives PRE-swizzled from qkv (sigma
// baked into global layout) so staging is straight f16x8 -> fewer LDS writes
// and bank conflicts. lsum on VALU, setprio around MFMA clusters.
__global__ __launch_bounds__(256, 2)
void attn_kernel(const _Float16* __restrict__ Q, const _Float16* __restrict__ K,
                 const _Float16* __restrict__ V, _Float16* __restrict__ O) {
  __shared__ __align__(16) _Float16 Ks[2][128][72];
  __shared__ __align__(16) _Float16 Vt[2][64][136]; // pitch 136: 16B-aligned rows

  const int t = threadIdx.x;
  const int lane = t & 63, wave = t >> 6;
  const int quad = lane >> 4, col = lane & 15;
  // XCD swizzle: id%8 = XCD (round-robin dispatch); give each XCD 2 whole bh
  const int id = blockIdx.y * 32 + blockIdx.x;
  const int xcd = id & 7, slot = id >> 3;
  const int bh = xcd * 2 + (slot >> 5);
  const int q0 = (slot & 31) * 128;
  const _Float16* Qb = Q + (size_t)bh * 4096 * 64;
  const _Float16* Kbh = K + (size_t)bh * 4096 * 64;
  const _Float16* Vg = V + (size_t)bh * 64 * 4096;   // [d][t'] pre-swizzled

  // staging coords
  const int sr = (t * 8) >> 6, sc = (t * 8) & 63;    // K rows: r = sr + 32*i
  const int vrow = t >> 4, vcol = (t & 15) * 8;      // V^T rows: d = vrow + 16*it

  // Q as B-fragment: B[n=query=mt*16+col][k=d=ks*32+quad*8+j]
  f16x8 qf[2][2];
#pragma unroll
  for (int mt = 0; mt < 2; mt++)
#pragma unroll
    for (int ks = 0; ks < 2; ks++)
      qf[mt][ks] = *(const f16x8*)&Qb[(size_t)(q0 + wave * 32 + mt * 16 + col) * 64 +
                                      ks * 32 + quad * 8];

  const f32x4 fz = {0.f, 0.f, 0.f, 0.f};

  f16x8 kreg[4], vreg[4];
  // prologue: load tile 0
#pragma unroll
  for (int i = 0; i < 4; i++)
    kreg[i] = *(const f16x8*)&Kbh[(size_t)(sr + 32 * i) * 64 + sc];
#pragma unroll
  for (int it = 0; it < 4; it++)
    vreg[it] = *(const f16x8*)&Vg[(size_t)(it * 16 + vrow) * 4096 + vcol];
#pragma unroll
  for (int i = 0; i < 4; i++)
    *(f16x8*)&Ks[0][sr + 32 * i][sc] = kreg[i];
#pragma unroll
  for (int it = 0; it < 4; it++)
    *(f16x8*)&Vt[0][it * 16 + vrow][vcol] = vreg[it];
  __syncthreads();

  // o_acc[mt][dt][r] = O^T[d=dt*16+quad*4+r][query=mt*16+col]
  f32x4 o_acc[2][4] = {};
  // per-lane partial row-sum of P for query=col, keys {nt*16+quad*4+r, all nt,j}
  float lsum[2] = {0.f, 0.f};

  for (int j = 0; j < 32; j++) {
    const int buf = j & 1;
    // prefetch tile j+1 into registers (latency hidden behind compute)
    if (j + 1 < 32) {
      const _Float16* Kb = Kbh + (size_t)(j + 1) * 128 * 64;
#pragma unroll
      for (int i = 0; i < 4; i++)
        kreg[i] = *(const f16x8*)&Kb[(size_t)(sr + 32 * i) * 64 + sc];
#pragma unroll
      for (int it = 0; it < 4; it++)
        vreg[it] = *(const f16x8*)&Vg[(size_t)(it * 16 + vrow) * 4096 +
                                      (j + 1) * 128 + vcol];
    }

    // S^T[key][query]: s[mt][nt][r] = S[q=mt*16+col][key=nt*16+quad*4+r]
    f32x4 s[2][8];
    __builtin_amdgcn_s_setprio(1);
#pragma unroll
    for (int nt = 0; nt < 8; nt++) {
      f16x8 kf = *(const f16x8*)&Ks[buf][nt * 16 + col][quad * 8];
#pragma unroll
      for (int mt = 0; mt < 2; mt++)
        s[mt][nt] = __builtin_amdgcn_mfma_f32_16x16x32_f16(kf, qf[mt][0], fz, 0, 0, 0);
    }
#pragma unroll
    for (int nt = 0; nt < 8; nt++) {
      f16x8 kf = *(const f16x8*)&Ks[buf][nt * 16 + col][32 + quad * 8];
#pragma unroll
      for (int mt = 0; mt < 2; mt++)
        s[mt][nt] = __builtin_amdgcn_mfma_f32_16x16x32_f16(kf, qf[mt][1], s[mt][nt], 0, 0, 0);
    }
    __builtin_amdgcn_s_setprio(0);

    // P = exp2(S^T): bare v_exp_f32 + packed f32->f16; l-accum on VALU pipe
    f16x4 pf[2][8];
#pragma unroll
    for (int mt = 0; mt < 2; mt++) {
#pragma unroll
      for (int nt = 0; nt < 8; nt++) {
        float p0 = fast_exp2(s[mt][nt][0]);
        float p1 = fast_exp2(s[mt][nt][1]);
        float p2 = fast_exp2(s[mt][nt][2]);
        float p3 = fast_exp2(s[mt][nt][3]);
        lsum[mt] += (p0 + p1) + (p2 + p3);
        union { f16x4 v4; f16x2 v2[2]; } u;
        u.v2[0] = pk_cvt(p0, p1);
        u.v2[1] = pk_cvt(p2, p3);
        pf[mt][nt] = u.v4;
      }
    }

    // O^T += V^T P^T at K=32: build 8-keys/lane P fragments via permlane32_swap
    __builtin_amdgcn_s_setprio(1);
#pragma unroll
    for (int u = 0; u < 4; u++) {
      f16x8 p8[2];
#pragma unroll
      for (int mt = 0; mt < 2; mt++) {
        union { f16x4 v; int d[2]; } X, Y;
        X.v = pf[mt][2 * u]; Y.v = pf[mt][2 * u + 1];
        int x0 = X.d[0], y0 = Y.d[0], x1 = X.d[1], y1 = Y.d[1];
        qswap32(x0, y0);   // x0 = low halves (j0,1), y0 = high halves (j4,5)
        qswap32(x1, y1);   // x1 = (j2,3),           y1 = (j6,7)
        union { int d[4]; f16x8 v; } P;
        P.d[0] = x0; P.d[1] = x1; P.d[2] = y0; P.d[3] = y1;
        p8[mt] = P.v;
      }
#pragma unroll
      for (int dt = 0; dt < 4; dt++) {
        f16x8 vf = *(const f16x8*)&Vt[buf][dt * 16 + col][u * 32 + quad * 8];
#pragma unroll
        for (int mt = 0; mt < 2; mt++)
          o_acc[mt][dt] = __builtin_amdgcn_mfma_f32_16x16x32_f16(vf, p8[mt], o_acc[mt][dt], 0, 0, 0);
      }
    }
    __builtin_amdgcn_s_setprio(0);

    // write prefetched tile into the other buffer; single barrier per iter
    if (j + 1 < 32) {
      const int nb = buf ^ 1;
#pragma unroll
      for (int i = 0; i < 4; i++)
        *(f16x8*)&Ks[nb][sr + 32 * i][sc] = kreg[i];
#pragma unroll
      for (int it = 0; it < 4; it++)
        *(f16x8*)&Vt[nb][it * 16 + vrow][vcol] = vreg[it];
      __syncthreads();
    }
  }

  // epilogue: complete l across quads (lanes col, col+16, col+32, col+48),
  // then O /= l, write [b][t][h*64+d] fp16 (row-major 8192x512)
  const int b = bh >> 3, h = bh & 7;
#pragma unroll
  for (int mt = 0; mt < 2; mt++) {
    float l = lsum[mt];
    l += __shfl_xor(l, 16, 64);
    l += __shfl_xor(l, 32, 64);
    int row = q0 + wave * 32 + mt * 16 + col;
    float inv = 1.0f / l;
#pragma unroll
    for (int dt = 0; dt < 4; dt++) {
      f16x4 ov;
#pragma unroll
      for (int r = 0; r < 4; r++) ov[r] = (_Float16)(o_acc[mt][dt][r] * inv);
      *(f16x4*)&O[((size_t)(b * 4096 + row)) * 512 + h * 64 + dt * 16 + quad * 4] = ov;
    }
  }
}

// ---------------- output projection: out = ao @ Wo^T + bo -> fp32 ----------
// R9-verified: 128x128 tile, reg-prefetch double-buffer (1 barrier/step),
// XCD swizzle, swapped-operand MFMA -> f32x4 stores of 4 consecutive n.
__global__ __launch_bounds__(256, 2)
void out_gemm(const _Float16* __restrict__ X, const _Float16* __restrict__ Wo,
              const float* __restrict__ bias, float* __restrict__ out) {
  __shared__ __align__(16) _Float16 As[2][128][72];
  __shared__ __align__(16) _Float16 Bs[2][128][72];
  // XCD swizzle (bijective, 256 = 8 xcd x 32)
  const int id = blockIdx.y * 64 + blockIdx.x;
  const int xcd = id & 7, s = id >> 3;          // s in [0,32)
  const int m0 = (xcd * 8 + (s & 7)) * 128;
  const int n0 = (s >> 3) * 128;

  const int t = threadIdx.x;
  const int lane = t & 63, wave = t >> 6;
  const int quad = lane >> 4, col = lane & 15;
  const int wm = (wave & 1) * 64, wn = (wave >> 1) * 64;
  const int sr = (t * 8) >> 6, sc = (t * 8) & 63;

  f32x4 acc[4][4] = {};
  f16x8 areg[4], breg[4];

#define OLOAD(K0)                                                             \
  {                                                                           \
    _Pragma("unroll") for (int i = 0; i < 4; i++) {                           \
      areg[i] = *(const f16x8*)&X[(size_t)(m0 + sr + 32 * i) * 512 + (K0) + sc]; \
      breg[i] = *(const f16x8*)&Wo[(size_t)(n0 + sr + 32 * i) * 512 + (K0) + sc]; \
    }                                                                         \
  }

#define OSTAGE(B)                                                             \
  {                                                                           \
    _Pragma("unroll") for (int i = 0; i < 4; i++) {                           \
      *(f16x8*)&As[(B)][sr + 32 * i][sc] = areg[i];                           \
      *(f16x8*)&Bs[(B)][sr + 32 * i][sc] = breg[i];                           \
    }                                                                         \
  }

#define OCOMP(B)                                                              \
  {                                                                           \
    _Pragma("unroll") for (int ks = 0; ks < 2; ks++) {                        \
      f16x8 a[4], b[4];                                                       \
      _Pragma("unroll") for (int i = 0; i < 4; i++) {                         \
        a[i] = *(const f16x8*)&As[(B)][wm + i * 16 + col][ks * 32 + quad * 8]; \
        b[i] = *(const f16x8*)&Bs[(B)][wn + i * 16 + col][ks * 32 + quad * 8]; \
      }                                                                       \
      _Pragma("unroll") for (int mi = 0; mi < 4; mi++)                        \
        _Pragma("unroll") for (int ni = 0; ni < 4; ni++)                      \
          acc[mi][ni] = __builtin_amdgcn_mfma_f32_16x16x32_f16(               \
              b[ni], a[mi], acc[mi][ni], 0, 0, 0);                            \
    }                                                                         \
  }

  OLOAD(0); OSTAGE(0); OLOAD(64);
  __syncthreads();
  OCOMP(0);
  OSTAGE(1); OLOAD(128); __syncthreads(); OCOMP(1);
  OSTAGE(0); OLOAD(192); __syncthreads(); OCOMP(0);
  OSTAGE(1); OLOAD(256); __syncthreads(); OCOMP(1);
  OSTAGE(0); OLOAD(320); __syncthreads(); OCOMP(0);
  OSTAGE(1); OLOAD(384); __syncthreads(); OCOMP(1);
  OSTAGE(0); OLOAD(448); __syncthreads(); OCOMP(0);
  OSTAGE(1); __syncthreads(); OCOMP(1);
#undef OLOAD
#undef OSTAGE
#undef OCOMP

  // swapped layout: acc[mi][ni][r] = out[m0+wm+mi*16+col][n0+wn+ni*16+quad*4+r]
#pragma unroll
  for (int ni = 0; ni < 4; ni++) {
    int nb = n0 + wn + ni * 16 + quad * 4;
    f32x4 bb = *(const f32x4*)&bias[nb];
#pragma unroll
    for (int mi = 0; mi < 4; mi++) {
      int m = m0 + wm + mi * 16 + col;
      f32x4 ov;
#pragma unroll
      for (int r = 0; r < 4; r++) ov[r] = acc[mi][ni][r] + bb[r];
      *(f32x4*)&out[(size_t)m * 512 + nb] = ov;
    }
  }
}

extern "C" void kernel_launch(void* const* d_in, const int* in_sizes, int n_in,
                              void* d_out, int out_size, void* d_ws, size_t ws_size,
                              hipStream_t stream) {
  const float* x  = (const float*)d_in[0];
  const float* Wq = (const float*)d_in[1];
  const float* bq = (const float*)d_in[2];
  const float* Wk = (const float*)d_in[3];
  const float* bk = (const float*)d_in[4];
  const float* Wv = (const float*)d_in[5];
  const float* bv = (const float*)d_in[6];
  const float* Wo = (const float*)d_in[7];
  const float* bo = (const float*)d_in[8];

  char* ws = (char*)d_ws;
  _Float16* xf  = (_Float16*)(ws);                 //  8 MiB: x as f16 (dead after qkv)
  _Float16* wf  = (_Float16*)(ws + (8u << 20));    //  2 MiB: Wq,Wk,Wv,Wo f16
  _Float16* qkv = (_Float16*)(ws + (10u << 20));   // 24 MiB: Q,K [bh][t][d]; V [bh][d][t']
  _Float16* ao  = (_Float16*)(ws);                 //  8 MiB: attn out (reuses xf)

  cvt_all<<<2560, 256, 0, stream>>>(x, Wq, Wk, Wv, Wo, xf, wf);

  qkv_gemm<<<dim3(64, 4, 3), 256, 0, stream>>>(xf, wf, bq, bk, bv, qkv);

  attn_kernel<<<dim3(32, 16), 256, 0, stream>>>(qkv, qkv + 4194304,
                                                qkv + 2 * 4194304, ao);

  out_gemm<<<dim3(64, 4), 256, 0, stream>>>(ao, wf + 3 * 262144, bo,
                                            (float*)d_out);
}